// Round 15
// baseline (97.381 us; speedup 1.0000x reference)
//
#include <hip/hip_runtime.h>
#include <math.h>

// Closed form derived from the reference:
//   q[n,0] = prod_{v=1..7} cos(x[n,v]+theta[v])
//   q[n,w] = prod_{v=0..w} cos(x[n,v]+theta[v])   (w = 1..7)
// Attention with E=8, no-max softmax (|score| <= 8/sqrt2), output scramble:
//   final[b,r,k] = sum_c att[b,(r%512)*8+c, r/512] * W[k,c] + bias[k].
//
// R14: 16x16x32 MFMA (4-reg C/D). The 32x32 shapes' 16-reg C forced the
//      accumulators into AGPRs (VGPR_Count=28 < o+cc) -> accvgpr traffic in
//      the VALU stream, and measured ~32cyc/inst in-situ. 16x16x32: QK has
//      C = f32x4 (t=4q+reg, s=lane&15); PV uses the permuted-k trick with
//      k-slot (q,j) -> t = (j<4 ? T0+4q+j : T1+4q+j-4): P goes cc->exp2->
//      pkrtz straight into the A-frag (no cross-lane), V^T read through the
//      same scramble (b64s at w*VSTR+T0+4q and +T1+4q). Q zeroed for quads
//      1..3 makes QK's k>=8 terms vanish (kf stays 8-wide). Denominator =
//      ones row w=8; lanes l15>8 clamp to it (garbage cols never read).
//      SROWS=64 (4 subtiles x 16 s), NTG=4, TPB=1024, grid 1024.

#define SEQ   4096
#define NB    16
#define SROWS 64           // s-rows per block (4 subtiles x 16)
#define TPB   1024
#define NTG   4            // t-groups
#define TC    1024         // t rows staged per chunk
#define NCH   (SEQ / TC)   // 4 chunks
#define PVG   8            // PV groups (32 t each) per wave per chunk
#define KSTR  12           // kf row stride in f16 (24 B)
#define VSTR  1028         // vt row stride in f16 (bank-offset 2 per row)

typedef _Float16 f16x4 __attribute__((ext_vector_type(4)));
typedef _Float16 f16x8 __attribute__((ext_vector_type(8)));
typedef float    f32x4 __attribute__((ext_vector_type(4)));
typedef __fp16   hf2   __attribute__((ext_vector_type(2)));

#if __has_builtin(__builtin_amdgcn_exp2f)
#define EXP2F(x) __builtin_amdgcn_exp2f(x)
#else
#define EXP2F(x) exp2f(x)
#endif

__global__ __launch_bounds__(TPB, 8)   // VGPR cap 64; 2 blocks/CU -> 32 waves/CU
void qattn_kernel(const float* __restrict__ x, const float* __restrict__ theta,
                  const float* __restrict__ wc, const float* __restrict__ bc,
                  float* __restrict__ out)
{
    __shared__ __align__(16) _Float16 kf[TC * KSTR];  // 24576 B: [t][8 f16 + 4 pad]
    __shared__ __align__(16) _Float16 vt[9 * VSTR];   // 18504 B: [w][t], w=8 = ones
    // after the last MFMA barrier these are re-used:
    float* part = (float*)kf;            // [NTG][SROWS][9] = 9216 B
    float* attn = (float*)vt;            // [SROWS][9]      = 2304 B

    const int tid  = threadIdx.x;
    const int lane = tid & 63;
    const int wv   = tid >> 6;           // 0..15
    const int sub  = wv & 3;             // s-subtile (16 rows)
    const int tg   = wv >> 2;            // t-group (256 t per chunk)
    const int l15  = lane & 15;
    const int q    = lane >> 4;          // quad 0..3

    const int b  = blockIdx.x >> 6;      // 64 blocks per batch
    const int S0 = (blockIdx.x & 63) * SROWS;
    const float* xb = x + (size_t)b * SEQ * 8;

    float th[8];
#pragma unroll
    for (int w = 0; w < 8; ++w) th[w] = theta[w];

    // ones (denominator) row: constant across chunks, write once.
    vt[8 * VSTR + tid] = (_Float16)1.0f;

    // ---- Q fragment (B of QK): B[k=8q+j][n=s=l15]; quads 1..3 = zeros ----
    f16x8 qfrag = {(_Float16)0.f, (_Float16)0.f, (_Float16)0.f, (_Float16)0.f,
                   (_Float16)0.f, (_Float16)0.f, (_Float16)0.f, (_Float16)0.f};
    {
        const int s = S0 + sub * 16 + l15;
        const float4 xa  = *(const float4*)(xb + s * 8);
        const float4 xb4 = *(const float4*)(xb + s * 8 + 4);
        float c0 = __cosf(xa.x  + th[0]);
        float c1 = __cosf(xa.y  + th[1]);
        float c2 = __cosf(xa.z  + th[2]);
        float c3 = __cosf(xa.w  + th[3]);
        float c4 = __cosf(xb4.x + th[4]);
        float c5 = __cosf(xb4.y + th[5]);
        float c6 = __cosf(xb4.z + th[6]);
        float c7 = __cosf(xb4.w + th[7]);
        float p1 = c0 * c1, p2 = p1 * c2, p3 = p2 * c3, p4 = p3 * c4;
        float p5 = p4 * c5, p6 = p5 * c6, p7 = p6 * c7;
        float p0 = c1 * c2 * c3 * c4 * c5 * c6 * c7;
        const float sc = 0.70710678118654752f * 1.44269504088896341f;
        if (q == 0)
            qfrag = (f16x8){(_Float16)(p0*sc), (_Float16)(p1*sc),
                            (_Float16)(p2*sc), (_Float16)(p3*sc),
                            (_Float16)(p4*sc), (_Float16)(p5*sc),
                            (_Float16)(p6*sc), (_Float16)(p7*sc)};
    }

    const f32x4 Z = {0.f, 0.f, 0.f, 0.f};
    f32x4 o = Z;                          // O[s'=4q+reg][w=l15], accumulated

    const int wr = (l15 < 8) ? l15 : 8;   // lanes w>=8 broadcast-read ones row
    // QK A (kf): row T + l15, k=0..7 (quads 1..3 don't-care: B=0 there)
    const _Float16* kfb = kf + (tg * 256 + l15) * KSTR;
    // PV B (vt): permuted-k scramble = +4q; immediates pg*32 (+16 for T1)
    const _Float16* vbb = vt + wr * VSTR + tg * 256 + 4 * q;

    for (int ch = 0; ch < NCH; ++ch) {
        __syncthreads();                  // previous chunk's readers done
        // ---- stage TC t-rows (1 per thread): kf wires + padded vt ----
        {
            const int t = ch * TC + tid;
            const float4 xa  = *(const float4*)(xb + t * 8);
            const float4 xb4 = *(const float4*)(xb + t * 8 + 4);
            float c0 = __cosf(xa.x  + th[0]);
            float c1 = __cosf(xa.y  + th[1]);
            float c2 = __cosf(xa.z  + th[2]);
            float c3 = __cosf(xa.w  + th[3]);
            float c4 = __cosf(xb4.x + th[4]);
            float c5 = __cosf(xb4.y + th[5]);
            float c6 = __cosf(xb4.z + th[6]);
            float c7 = __cosf(xb4.w + th[7]);
            float p1 = c0 * c1, p2 = p1 * c2, p3 = p2 * c3, p4 = p3 * c4;
            float p5 = p4 * c5, p6 = p5 * c6, p7 = p6 * c7;
            float p0 = c1 * c2 * c3 * c4 * c5 * c6 * c7;
            _Float16 h0 = (_Float16)p0, h1 = (_Float16)p1, h2 = (_Float16)p2,
                     h3 = (_Float16)p3, h4 = (_Float16)p4, h5 = (_Float16)p5,
                     h6 = (_Float16)p6, h7 = (_Float16)p7;
            _Float16* krow = kf + tid * KSTR;
            *(f16x4*)(krow)     = (f16x4){h0, h1, h2, h3};
            *(f16x4*)(krow + 4) = (f16x4){h4, h5, h6, h7};
            vt[0 * VSTR + tid] = h0;
            vt[1 * VSTR + tid] = h1;
            vt[2 * VSTR + tid] = h2;
            vt[3 * VSTR + tid] = h3;
            vt[4 * VSTR + tid] = h4;
            vt[5 * VSTR + tid] = h5;
            vt[6 * VSTR + tid] = h6;
            vt[7 * VSTR + tid] = h7;
        }
        __syncthreads();
        // ---- 8 PV groups: 2 QK(16x16x32) -> exp2/pkrtz -> 1 PV(16x16x32) ----
#pragma unroll
        for (int pg = 0; pg < PVG; ++pg) {
            const _Float16* kp = kfb + pg * 32 * KSTR;
            union { f16x4 h[2]; f16x8 v; } k0, k1;
            k0.h[0] = *(const f16x4*)(kp);
            k0.h[1] = *(const f16x4*)(kp + 4);
            k1.h[0] = *(const f16x4*)(kp + 16 * KSTR);
            k1.h[1] = *(const f16x4*)(kp + 16 * KSTR + 4);
            f32x4 cc0 = __builtin_amdgcn_mfma_f32_16x16x32_f16(k0.v, qfrag, Z, 0, 0, 0);
            f32x4 cc1 = __builtin_amdgcn_mfma_f32_16x16x32_f16(k1.v, qfrag, Z, 0, 0, 0);
            // P A-frag: k-slot (q,j) -> t = (j<4 ? T0+4q+j : T1+4q+j-4)
            union { int i_[4]; f16x8 v; } A;
            {
                union { hf2 h; int i_; } t2;
                t2.h = __builtin_amdgcn_cvt_pkrtz(EXP2F(cc0.x), EXP2F(cc0.y)); A.i_[0] = t2.i_;
                t2.h = __builtin_amdgcn_cvt_pkrtz(EXP2F(cc0.z), EXP2F(cc0.w)); A.i_[1] = t2.i_;
                t2.h = __builtin_amdgcn_cvt_pkrtz(EXP2F(cc1.x), EXP2F(cc1.y)); A.i_[2] = t2.i_;
                t2.h = __builtin_amdgcn_cvt_pkrtz(EXP2F(cc1.z), EXP2F(cc1.w)); A.i_[3] = t2.i_;
            }
            // V^T through the same k-scramble: b64s at +pg*32 and +pg*32+16
            union { f16x4 h[2]; f16x8 v; } Bv;
            Bv.h[0] = *(const f16x4*)(vbb + pg * 32);
            Bv.h[1] = *(const f16x4*)(vbb + pg * 32 + 16);
            o = __builtin_amdgcn_mfma_f32_16x16x32_f16(A.v, Bv.v, o, 0, 0, 0);
        }
    }

    // ---- write per-t-group partials (cols 0..8; col 8 = exp-sum) ----
    __syncthreads();                      // all MFMA reads of kf/vt done; alias now
    if (l15 < 9) {
#pragma unroll
        for (int r = 0; r < 4; ++r) {
            const int sloc = sub * 16 + 4 * q + r;
            part[((tg * SROWS) + sloc) * 9 + l15] = o[r];
        }
    }
    __syncthreads();
    // ---- reduce over t-groups (576 entries) ----
    if (tid < SROWS * 9) {
        const int rr = tid / 9;
        const int w  = tid - rr * 9;
        float sm = 0.f;
#pragma unroll
        for (int g = 0; g < NTG; ++g) sm += part[((g * SROWS) + rr) * 9 + w];
        attn[rr * 9 + w] = sm;
    }
    __syncthreads();
    if (tid < SROWS * 8) {                // normalize in place (col 8 untouched)
        const int rr = tid >> 3;
        const int w  = tid & 7;
        attn[rr * 9 + w] = attn[rr * 9 + w] / attn[rr * 9 + 8];
    }
    __syncthreads();

    // ---- epilogue: swapaxes/reshape scramble + 8x8 combine ----
    if (tid < SROWS) {
        const int e    = tid >> 3;        // wire
        const int nloc = tid & 7;
        const int r    = e * 512 + (S0 >> 3) + nloc;
        float y[8];
#pragma unroll
        for (int c = 0; c < 8; ++c) y[c] = attn[(nloc * 8 + c) * 9 + e];
        float oo[8];
#pragma unroll
        for (int k = 0; k < 8; ++k) {
            float a = bc[k];
#pragma unroll
            for (int c = 0; c < 8; ++c) a += y[c] * wc[k * 8 + c];
            oo[k] = a;
        }
        float4* op = (float4*)(out + ((size_t)b * SEQ + r) * 8);
        op[0] = make_float4(oo[0], oo[1], oo[2], oo[3]);
        op[1] = make_float4(oo[4], oo[5], oo[6], oo[7]);
    }
}

extern "C" void kernel_launch(void* const* d_in, const int* in_sizes, int n_in,
                              void* d_out, int out_size, void* d_ws, size_t ws_size,
                              hipStream_t stream)
{
    const float* x  = (const float*)d_in[0];
    const float* th = (const float*)d_in[1];
    const float* wc = (const float*)d_in[2];
    const float* bc = (const float*)d_in[3];
    float* out = (float*)d_out;

    qattn_kernel<<<dim3(NB * (SEQ / SROWS)), dim3(TPB), 0, stream>>>(x, th, wc, bc, out);
}